// Round 4
// baseline (260.493 us; speedup 1.0000x reference)
//
#include <hip/hip_runtime.h>
#include <cstdint>

typedef __bf16 bf16;
typedef __bf16 bf16x2 __attribute__((ext_vector_type(2)));
typedef __bf16 bf16x4 __attribute__((ext_vector_type(4)));
typedef __bf16 bf16x8 __attribute__((ext_vector_type(8)));
typedef float f32x4 __attribute__((ext_vector_type(4)));
typedef uint32_t u32x2 __attribute__((ext_vector_type(2)));

#define MFMA16(a, b, c) __builtin_amdgcn_mfma_f32_16x16x32_bf16(a, b, c, 0, 0, 0)

static constexpr int N = 4096;    // 64*64 tokens
static constexpr int CDIM = 128;  // channels
static constexpr int NH = 4;      // heads
static constexpr int DH = 32;     // dim per head

// pack high halves of two f32 (truncate-to-bf16): result = {bf16(a) lo, bf16(b) hi}
__device__ __forceinline__ uint32_t pack_bf16_trunc(float a, float b) {
    return __builtin_amdgcn_perm(__builtin_bit_cast(uint32_t, b),
                                 __builtin_bit_cast(uint32_t, a), 0x07060302u);
}

// round-half-up f32 -> bf16 (cheap scalar cvt for inputs/weights)
__device__ __forceinline__ bf16 to_bf16_rnd(float f) {
    uint32_t u = __builtin_bit_cast(uint32_t, f);
    return __builtin_bit_cast(bf16, (uint16_t)((u + 0x8000u) >> 16));
}

// ---------------- weight convert (fold scale*log2e into wq) ----------------
__global__ __launch_bounds__(256) void cvt_w(const float* __restrict__ wq,
                                             const float* __restrict__ wk,
                                             const float* __restrict__ wv,
                                             const float* __restrict__ wo,
                                             bf16* __restrict__ W) {
    int i = blockIdx.x * 256 + threadIdx.x;  // 0..16383
    const float qs = 0.17677669529663687f * 1.4426950408889634f;  // 32^-0.5 * log2(e)
    W[i]         = (bf16)(wq[i] * qs);
    W[16384 + i] = to_bf16_rnd(wk[i]);
    W[32768 + i] = to_bf16_rnd(wv[i]);
    W[49152 + i] = to_bf16_rnd(wo[i]);
}

// ---------------- QKV projection ----------------
// x: [b][128][4096] f32.  Out: Q,K as [b*4+h][n][32] bf16 ; V as [b][128][n] bf16.
// grid.z = wt (0:Q 1:K 2:V)
__global__ __launch_bounds__(256) void proj_qkv(const float* __restrict__ x,
                                                const bf16* __restrict__ W,
                                                bf16* __restrict__ Q,
                                                bf16* __restrict__ K,
                                                bf16* __restrict__ V) {
    const int b = blockIdx.y;
    const int wt = blockIdx.z;
    const int n0 = blockIdx.x * 64;
    __shared__ __align__(16) bf16 xT[64][136];  // [n][c], padded (16B rows)
    const int tid = threadIdx.x;
    const float* xb = x + (size_t)b * CDIM * N;
    for (int i = tid; i < 64 * 128; i += 256) {
        int n = i & 63, cc = i >> 6;
        xT[n][cc] = to_bf16_rnd(xb[(size_t)cc * N + n0 + n]);
    }
    __syncthreads();

    const int lane = tid & 63, w = tid >> 6;
    const int cr = lane & 15, quad = lane >> 4;

    const bf16* Wm = W + wt * 16384;
    for (int nt = 0; nt < 4; ++nt) {
        bf16x8 bfr[4];
#pragma unroll
        for (int ks = 0; ks < 4; ++ks)
            bfr[ks] = *(const bf16x8*)&xT[nt * 16 + cr][ks * 32 + quad * 8];
#pragma unroll
        for (int ot2 = 0; ot2 < 2; ++ot2) {
            int ot = w * 2 + ot2;
            f32x4 acc = {0.f, 0.f, 0.f, 0.f};
#pragma unroll
            for (int ks = 0; ks < 4; ++ks) {
                bf16x8 afr = *(const bf16x8*)&Wm[(ot * 16 + cr) * 128 + ks * 32 + quad * 8];
                acc = MFMA16(afr, bfr[ks], acc);
            }
            // D: row(o) = ot*16 + quad*4 + r ; col(n) = cr
            int n = n0 + nt * 16 + cr;
            int o0 = ot * 16 + quad * 4;
            if (wt < 2) {
                bf16* dst = (wt == 0) ? Q : K;
                int h = o0 >> 5, d0 = o0 & 31;
                bf16* p = dst + (((size_t)(b * NH + h) * N + n) * DH + d0);
                *(bf16x2*)p       = (bf16x2){(bf16)acc[0], (bf16)acc[1]};
                *(bf16x2*)(p + 2) = (bf16x2){(bf16)acc[2], (bf16)acc[3]};
            } else {
#pragma unroll
                for (int r = 0; r < 4; ++r)
                    V[((size_t)b * CDIM + o0 + r) * N + n] = (bf16)acc[r];
            }
        }
    }
}

// ---------------- flash attention (split-K x2 for occupancy) ----------------
// Q,K: [bh][n][32] (wq pre-scaled by 32^-.5*log2e) ; V: [bh*32+d][n] ; O: [b][n][128] bf16.
// 2048 blocks; bh = gid&15 (XCD swizzle). Block = 2 q-tiles x 2 key-halves.
// Wave w: q-tile = w>>1, key-half = w&1. No running max => partials add linearly.
__global__ __launch_bounds__(256, 8) void flash(const bf16* __restrict__ Q,
                                                const bf16* __restrict__ K,
                                                const bf16* __restrict__ V,
                                                bf16* __restrict__ O) {
    const int gid = blockIdx.x;
    const int bh = gid & 15;
    const int w = threadIdx.x >> 6, lane = threadIdx.x & 63;
    const int cr = lane & 15, quad = lane >> 4;
    const int pair = w >> 1, half = w & 1;
    const int q0 = (gid >> 4) * 32 + pair * 16;

    // per-wave P buffers: [wave][sub(2)][q(16)][keys padded to 40]
    __shared__ __align__(16) bf16 plds[4][2][16][40];
    __shared__ float red[2][64][9];  // partial O (8) + partial l (1) per lane
    bf16* wbase = &plds[w][0][0][0];
    const int wr_off = cr * 40 + quad * 4;
    const int rd_off = cr * 40 + quad * 8;

    const bf16* Qb = Q + (size_t)bh * N * DH;
    const bf16* Kb = K + (size_t)bh * N * DH;
    const bf16* Vb = V + (size_t)bh * DH * N;

    const bf16x8 qf = *(const bf16x8*)&Qb[(q0 + cr) * DH + quad * 8];
    const bf16* kr = Kb + cr * DH + quad * 8;
    const bf16* vr0 = Vb + (size_t)cr * N + quad * 8;
    const bf16* vr1 = Vb + (size_t)(16 + cr) * N + quad * 8;

    bf16x8 ones;
#pragma unroll
    for (int i = 0; i < 8; ++i) ones[i] = (bf16)1.0f;

    f32x4 acc0 = {0.f, 0.f, 0.f, 0.f};
    f32x4 acc1 = {0.f, 0.f, 0.f, 0.f};
    f32x4 accL = {0.f, 0.f, 0.f, 0.f};

    const int kbeg = half * (N / 2), kend = kbeg + N / 2;
#pragma unroll 2
    for (int kb = kbeg; kb < kend; kb += 64) {
#pragma unroll
        for (int j = 0; j < 2; ++j) {
            int kk = kb + j * 32;
            bf16x8 k0 = *(const bf16x8*)&kr[(size_t)kk * DH];
            bf16x8 k1 = *(const bf16x8*)&kr[(size_t)(kk + 16) * DH];
            bf16x8 v0 = *(const bf16x8*)&vr0[kk];
            bf16x8 v1 = *(const bf16x8*)&vr1[kk];

            f32x4 z = {0.f, 0.f, 0.f, 0.f};
            f32x4 s0 = MFMA16(k0, qf, z);  // S^T[key=quad*4+r][q=cr]
            f32x4 s1 = MFMA16(k1, qf, z);  // keys +16..31

            float e00 = __builtin_amdgcn_exp2f(s0[0]);
            float e01 = __builtin_amdgcn_exp2f(s0[1]);
            float e02 = __builtin_amdgcn_exp2f(s0[2]);
            float e03 = __builtin_amdgcn_exp2f(s0[3]);
            float e10 = __builtin_amdgcn_exp2f(s1[0]);
            float e11 = __builtin_amdgcn_exp2f(s1[1]);
            float e12 = __builtin_amdgcn_exp2f(s1[2]);
            float e13 = __builtin_amdgcn_exp2f(s1[3]);

            uint32_t d0 = pack_bf16_trunc(e00, e01);
            uint32_t d1 = pack_bf16_trunc(e02, e03);
            uint32_t d2 = pack_bf16_trunc(e10, e11);
            uint32_t d3 = pack_bf16_trunc(e12, e13);

            bf16* pw = wbase + j * 640 + wr_off;
            *(u32x2*)pw        = (u32x2){d0, d1};
            *(u32x2*)(pw + 16) = (u32x2){d2, d3};

            bf16x8 pf = *(const bf16x8*)(wbase + j * 640 + rd_off);

            acc0 = MFMA16(v0, pf, acc0);   // out^T[d=quad*4+r][q=cr], d 0..15
            acc1 = MFMA16(v1, pf, acc1);   // d 16..31
            accL = MFMA16(ones, pf, accL); // row-sum of P
        }
    }

    // combine key-halves: half 1 publishes, half 0 reduces + stores
    if (half == 1) {
        float* r = red[pair][lane];
        r[0] = acc0[0]; r[1] = acc0[1]; r[2] = acc0[2]; r[3] = acc0[3];
        r[4] = acc1[0]; r[5] = acc1[1]; r[6] = acc1[2]; r[7] = acc1[3];
        r[8] = accL[0];
    }
    __syncthreads();
    if (half == 0) {
        const float* r = red[pair][lane];
        acc0[0] += r[0]; acc0[1] += r[1]; acc0[2] += r[2]; acc0[3] += r[3];
        acc1[0] += r[4]; acc1[1] += r[5]; acc1[2] += r[6]; acc1[3] += r[7];
        float inv = __builtin_amdgcn_rcpf(accL[0] + r[8]);

        const int b = bh >> 2, h = bh & 3;
        bf16* Ob = O + ((size_t)b * N + q0 + cr) * CDIM + h * DH;
        const int d0 = quad * 4;
        *(bf16x2*)(Ob + d0)      = (bf16x2){(bf16)(acc0[0] * inv), (bf16)(acc0[1] * inv)};
        *(bf16x2*)(Ob + d0 + 2)  = (bf16x2){(bf16)(acc0[2] * inv), (bf16)(acc0[3] * inv)};
        *(bf16x2*)(Ob + 16 + d0) = (bf16x2){(bf16)(acc1[0] * inv), (bf16)(acc1[1] * inv)};
        *(bf16x2*)(Ob + 18 + d0) = (bf16x2){(bf16)(acc1[2] * inv), (bf16)(acc1[3] * inv)};
    }
}

// ---------------- output projection ----------------
// A: [b][n][128] bf16 ; out: [b][128][4096] f32 with bias. grid.z splits ot.
__global__ __launch_bounds__(256) void proj_o(const bf16* __restrict__ A,
                                              const bf16* __restrict__ W,
                                              const float* __restrict__ bo,
                                              float* __restrict__ out) {
    const int b = blockIdx.y;
    const int n0 = blockIdx.x * 64;
    __shared__ __align__(16) bf16 aT[64][136];  // [n][c]
    const int tid = threadIdx.x;
    const bf16* Ab = A + (size_t)b * N * CDIM;
    for (int i = tid; i < 64 * 64; i += 256) {
        int c2 = i & 63, n = i >> 6;
        *(uint32_t*)&aT[n][c2 * 2] = *(const uint32_t*)&Ab[(size_t)(n0 + n) * CDIM + c2 * 2];
    }
    __syncthreads();

    const int lane = tid & 63, w = tid >> 6;
    const int cr = lane & 15, quad = lane >> 4;
    const bf16* Wm = W + 3 * 16384;  // wo
    const int ot = blockIdx.z * 4 + w;

    for (int nt = 0; nt < 4; ++nt) {
        bf16x8 bfr[4];
#pragma unroll
        for (int ks = 0; ks < 4; ++ks)
            bfr[ks] = *(const bf16x8*)&aT[nt * 16 + cr][ks * 32 + quad * 8];
        f32x4 acc = {0.f, 0.f, 0.f, 0.f};
#pragma unroll
        for (int ks = 0; ks < 4; ++ks) {
            bf16x8 afr = *(const bf16x8*)&Wm[(ot * 16 + cr) * 128 + ks * 32 + quad * 8];
            acc = MFMA16(afr, bfr[ks], acc);
        }
        int n = n0 + nt * 16 + cr;
        int o0 = ot * 16 + quad * 4;
#pragma unroll
        for (int r = 0; r < 4; ++r)
            out[((size_t)b * CDIM + o0 + r) * N + n] = acc[r] + bo[o0 + r];
    }
}

// ---------------- launch ----------------
extern "C" void kernel_launch(void* const* d_in, const int* in_sizes, int n_in,
                              void* d_out, int out_size, void* d_ws, size_t ws_size,
                              hipStream_t stream) {
    const float* x  = (const float*)d_in[0];
    const float* wq = (const float*)d_in[1];
    const float* wk = (const float*)d_in[2];
    const float* wv = (const float*)d_in[3];
    const float* wo = (const float*)d_in[4];
    const float* bo = (const float*)d_in[5];

    char* ws = (char*)d_ws;
    bf16* Q = (bf16*)(ws);                       // 4 MB  [bh][n][32]
    bf16* K = (bf16*)(ws + ((size_t)4 << 20));   // 4 MB
    bf16* V = (bf16*)(ws + ((size_t)8 << 20));   // 4 MB  [b][128][n]
    bf16* A = (bf16*)(ws + ((size_t)12 << 20));  // 4 MB  [b][n][128]
    bf16* W = (bf16*)(ws + ((size_t)16 << 20));  // 128 KB

    cvt_w<<<64, 256, 0, stream>>>(wq, wk, wv, wo, W);
    proj_qkv<<<dim3(64, 4, 3), 256, 0, stream>>>(x, W, Q, K, V);
    flash<<<2048, 256, 0, stream>>>(Q, K, V, A);
    proj_o<<<dim3(64, 4, 2), 256, 0, stream>>>(A, W, bo, (float*)d_out);
}

// Round 5
// 153.087 us; speedup vs baseline: 1.7016x; 1.7016x over previous
//
#include <hip/hip_runtime.h>
#include <cstdint>

typedef __bf16 bf16;
typedef __bf16 bf16x2 __attribute__((ext_vector_type(2)));
typedef __bf16 bf16x4 __attribute__((ext_vector_type(4)));
typedef __bf16 bf16x8 __attribute__((ext_vector_type(8)));
typedef float f32x4 __attribute__((ext_vector_type(4)));

#define MFMA16(a, b, c) __builtin_amdgcn_mfma_f32_16x16x32_bf16(a, b, c, 0, 0, 0)

static constexpr int N = 4096;    // 64*64 tokens
static constexpr int CDIM = 128;  // channels
static constexpr int NH = 4;      // heads
static constexpr int DH = 32;     // dim per head

// pack high halves of two f32 (truncate-to-bf16): {bf16(a) lo, bf16(b) hi}
__device__ __forceinline__ uint32_t pack_bf16_trunc(float a, float b) {
    return __builtin_amdgcn_perm(__builtin_bit_cast(uint32_t, b),
                                 __builtin_bit_cast(uint32_t, a), 0x07060302u);
}

__device__ __forceinline__ bf16 to_bf16_rnd(float f) {
    uint32_t u = __builtin_bit_cast(uint32_t, f);
    return __builtin_bit_cast(bf16, (uint16_t)((u + 0x8000u) >> 16));
}

// ---------------- weight convert (fold scale*log2e into wq) ----------------
__global__ __launch_bounds__(256) void cvt_w(const float* __restrict__ wq,
                                             const float* __restrict__ wk,
                                             const float* __restrict__ wv,
                                             const float* __restrict__ wo,
                                             bf16* __restrict__ W) {
    int i = blockIdx.x * 256 + threadIdx.x;  // 0..16383
    const float qs = 0.17677669529663687f * 1.4426950408889634f;  // 32^-0.5 * log2(e)
    W[i]         = (bf16)(wq[i] * qs);
    W[16384 + i] = to_bf16_rnd(wk[i]);
    W[32768 + i] = to_bf16_rnd(wv[i]);
    W[49152 + i] = to_bf16_rnd(wo[i]);
}

// ---------------- QKV projection ----------------
// x: [b][128][4096] f32.  Out: Q,K as [b*4+h][n][32] bf16 ;
// V TILED: [bh][tile=n>>6][d=32][k=n&63] bf16 (4 KB contiguous per 64-key tile).
// grid.z = wt (0:Q 1:K 2:V)
__global__ __launch_bounds__(256) void proj_qkv(const float* __restrict__ x,
                                                const bf16* __restrict__ W,
                                                bf16* __restrict__ Q,
                                                bf16* __restrict__ K,
                                                bf16* __restrict__ V) {
    const int b = blockIdx.y;
    const int wt = blockIdx.z;
    const int n0 = blockIdx.x * 64;
    __shared__ __align__(16) bf16 xT[64][136];  // [n][c], padded
    const int tid = threadIdx.x;
    const float* xb = x + (size_t)b * CDIM * N;
    for (int i = tid; i < 64 * 128; i += 256) {
        int n = i & 63, cc = i >> 6;
        xT[n][cc] = to_bf16_rnd(xb[(size_t)cc * N + n0 + n]);
    }
    __syncthreads();

    const int lane = tid & 63, w = tid >> 6;
    const int cr = lane & 15, quad = lane >> 4;

    const bf16* Wm = W + wt * 16384;
    for (int nt = 0; nt < 4; ++nt) {
        bf16x8 bfr[4];
#pragma unroll
        for (int ks = 0; ks < 4; ++ks)
            bfr[ks] = *(const bf16x8*)&xT[nt * 16 + cr][ks * 32 + quad * 8];
#pragma unroll
        for (int ot2 = 0; ot2 < 2; ++ot2) {
            int ot = w * 2 + ot2;
            f32x4 acc = {0.f, 0.f, 0.f, 0.f};
#pragma unroll
            for (int ks = 0; ks < 4; ++ks) {
                bf16x8 afr = *(const bf16x8*)&Wm[(ot * 16 + cr) * 128 + ks * 32 + quad * 8];
                acc = MFMA16(afr, bfr[ks], acc);
            }
            // D: row(o) = ot*16 + quad*4 + r ; col(n) = cr
            int n = n0 + nt * 16 + cr;
            int o0 = ot * 16 + quad * 4;
            if (wt < 2) {
                bf16* dst = (wt == 0) ? Q : K;
                int h = o0 >> 5, d0 = o0 & 31;
                bf16* p = dst + (((size_t)(b * NH + h) * N + n) * DH + d0);
                *(bf16x2*)p       = (bf16x2){(bf16)acc[0], (bf16)acc[1]};
                *(bf16x2*)(p + 2) = (bf16x2){(bf16)acc[2], (bf16)acc[3]};
            } else {
                int h = o0 >> 5, d0 = o0 & 31;
                int k6 = nt * 16 + cr;
                bf16* p = V + ((size_t)(b * NH + h) * 64 + blockIdx.x) * 2048 + k6;
#pragma unroll
                for (int r = 0; r < 4; ++r)
                    p[(d0 + r) * 64] = (bf16)acc[r];
            }
        }
    }
}

// ---------------- flash attention (LDS-staged K/V tiles) ----------------
// Q,K: [bh][n][32] (wq pre-scaled) ; V tiled [bh][tile][d32][k64] ; O: [b][n][128].
// 512 blocks (= 2/CU). Block = 128 queries (4 waves x 32q). bh = gid&15 (XCD swizzle).
// Per 64-key tile: cooperative stage of K(4KB)+V(4KB) into padded LDS; one barrier/tile.
__global__ __launch_bounds__(256, 2) void flash(const bf16* __restrict__ Q,
                                                const bf16* __restrict__ K,
                                                const bf16* __restrict__ V,
                                                bf16* __restrict__ O) {
    const int gid = blockIdx.x;
    const int bh = gid & 15;
    const int tid = threadIdx.x;
    const int w = tid >> 6, lane = tid & 63;
    const int cr = lane & 15, quad = lane >> 4;
    const int q0w = (gid >> 4) * 128 + w * 32;

    // padded LDS: K rows 80B (40 bf16), V rows 144B (72 bf16), P rows 144B
    __shared__ __align__(16) bf16 Kl[2][64 * 40];
    __shared__ __align__(16) bf16 Vl[2][32 * 72];
    __shared__ __align__(16) bf16 Pb[4][2][16 * 72];

    const bf16* Qb = Q + (size_t)bh * N * DH;
    const bf16* Kb = K + (size_t)bh * N * DH;
    const bf16* Vt = V + (size_t)bh * 64 * 2048;

    // staging assignments (per thread: one 16B K chunk + one 16B V chunk)
    const int k_dst = (tid >> 2) * 40 + (tid & 3) * 8;   // key=tid>>2, 16B chunk tid&3
    const int v_dst = (tid >> 3) * 72 + (tid & 7) * 8;   // d=tid>>3, 16B chunk tid&7

    bf16x8 qf[2];
#pragma unroll
    for (int g = 0; g < 2; ++g)
        qf[g] = *(const bf16x8*)&Qb[(q0w + g * 16 + cr) * DH + quad * 8];

    bf16x8 ones;
#pragma unroll
    for (int i = 0; i < 8; ++i) ones[i] = (bf16)1.0f;

    f32x4 acc00 = {0,0,0,0}, acc01 = {0,0,0,0};
    f32x4 acc10 = {0,0,0,0}, acc11 = {0,0,0,0};
    f32x4 accL0 = {0,0,0,0}, accL1 = {0,0,0,0};

    // preload tile 0
    {
        bf16x8 kreg = *(const bf16x8*)(Kb + tid * 8);
        bf16x8 vreg = *(const bf16x8*)(Vt + tid * 8);
        *(bf16x8*)&Kl[0][k_dst] = kreg;
        *(bf16x8*)&Vl[0][v_dst] = vreg;
    }
    __syncthreads();

    for (int kt = 0; kt < 64; ++kt) {
        const int cb = kt & 1;
        bf16x8 kreg, vreg;
        if (kt < 63) {
            kreg = *(const bf16x8*)(Kb + (kt + 1) * 2048 + tid * 8);
            vreg = *(const bf16x8*)(Vt + (kt + 1) * 2048 + tid * 8);
        }
        const bf16* Kc = &Kl[cb][0];
        const bf16* Vc = &Vl[cb][0];
        bf16* myP0 = &Pb[w][0][cr * 72];
        bf16* myP1 = &Pb[w][1][cr * 72];

        // ---- S phase: S^T = K·Q^T, exp2, pack to P^T[q][key] ----
#pragma unroll
        for (int kg = 0; kg < 4; ++kg) {
            bf16x8 ak = *(const bf16x8*)&Kc[(kg * 16 + cr) * 40 + quad * 8];
            f32x4 z = {0,0,0,0};
            f32x4 s0 = MFMA16(ak, qf[0], z);  // [key=kg*16+quad*4+r][q=cr]
            f32x4 s1 = MFMA16(ak, qf[1], z);

            uint32_t a0 = pack_bf16_trunc(__builtin_amdgcn_exp2f(s0[0]),
                                          __builtin_amdgcn_exp2f(s0[1]));
            uint32_t a1 = pack_bf16_trunc(__builtin_amdgcn_exp2f(s0[2]),
                                          __builtin_amdgcn_exp2f(s0[3]));
            uint32_t b0 = pack_bf16_trunc(__builtin_amdgcn_exp2f(s1[0]),
                                          __builtin_amdgcn_exp2f(s1[1]));
            uint32_t b1 = pack_bf16_trunc(__builtin_amdgcn_exp2f(s1[2]),
                                          __builtin_amdgcn_exp2f(s1[3]));

            *(bf16x4*)(myP0 + kg * 16 + quad * 4) =
                __builtin_bit_cast(bf16x4, (uint64_t)a0 | ((uint64_t)a1 << 32));
            *(bf16x4*)(myP1 + kg * 16 + quad * 4) =
                __builtin_bit_cast(bf16x4, (uint64_t)b0 | ((uint64_t)b1 << 32));
        }

        // ---- PV phase ----
#pragma unroll
        for (int kv = 0; kv < 2; ++kv) {
            bf16x8 pf0 = *(const bf16x8*)(myP0 + kv * 32 + quad * 8);
            bf16x8 pf1 = *(const bf16x8*)(myP1 + kv * 32 + quad * 8);
            bf16x8 av0 = *(const bf16x8*)&Vc[cr * 72 + kv * 32 + quad * 8];        // d 0..15
            bf16x8 av1 = *(const bf16x8*)&Vc[(16 + cr) * 72 + kv * 32 + quad * 8]; // d 16..31
            acc00 = MFMA16(av0, pf0, acc00);
            acc01 = MFMA16(av1, pf0, acc01);
            acc10 = MFMA16(av0, pf1, acc10);
            acc11 = MFMA16(av1, pf1, acc11);
            accL0 = MFMA16(ones, pf0, accL0);
            accL1 = MFMA16(ones, pf1, accL1);
        }

        if (kt < 63) {
            *(bf16x8*)&Kl[1 - cb][k_dst] = kreg;
            *(bf16x8*)&Vl[1 - cb][v_dst] = vreg;
        }
        __syncthreads();
    }

    const int b = bh >> 2, h = bh & 3;
    const int d0 = quad * 4;
#pragma unroll
    for (int g = 0; g < 2; ++g) {
        f32x4 a0 = g ? acc10 : acc00;
        f32x4 a1 = g ? acc11 : acc01;
        float l = g ? accL1[0] : accL0[0];
        float inv = __builtin_amdgcn_rcpf(l);
        bf16* Ob = O + ((size_t)b * N + q0w + g * 16 + cr) * CDIM + h * DH;
        *(bf16x2*)(Ob + d0)      = (bf16x2){(bf16)(a0[0] * inv), (bf16)(a0[1] * inv)};
        *(bf16x2*)(Ob + d0 + 2)  = (bf16x2){(bf16)(a0[2] * inv), (bf16)(a0[3] * inv)};
        *(bf16x2*)(Ob + 16 + d0) = (bf16x2){(bf16)(a1[0] * inv), (bf16)(a1[1] * inv)};
        *(bf16x2*)(Ob + 18 + d0) = (bf16x2){(bf16)(a1[2] * inv), (bf16)(a1[3] * inv)};
    }
}

// ---------------- output projection ----------------
// A: [b][n][128] bf16 ; out: [b][128][4096] f32 with bias. grid.z splits ot.
__global__ __launch_bounds__(256) void proj_o(const bf16* __restrict__ A,
                                              const bf16* __restrict__ W,
                                              const float* __restrict__ bo,
                                              float* __restrict__ out) {
    const int b = blockIdx.y;
    const int n0 = blockIdx.x * 64;
    __shared__ __align__(16) bf16 aT[64][136];  // [n][c]
    const int tid = threadIdx.x;
    const bf16* Ab = A + (size_t)b * N * CDIM;
    for (int i = tid; i < 64 * 64; i += 256) {
        int c2 = i & 63, n = i >> 6;
        *(uint32_t*)&aT[n][c2 * 2] = *(const uint32_t*)&Ab[(size_t)(n0 + n) * CDIM + c2 * 2];
    }
    __syncthreads();

    const int lane = tid & 63, w = tid >> 6;
    const int cr = lane & 15, quad = lane >> 4;
    const bf16* Wm = W + 3 * 16384;  // wo
    const int ot = blockIdx.z * 4 + w;

    for (int nt = 0; nt < 4; ++nt) {
        bf16x8 bfr[4];
#pragma unroll
        for (int ks = 0; ks < 4; ++ks)
            bfr[ks] = *(const bf16x8*)&aT[nt * 16 + cr][ks * 32 + quad * 8];
        f32x4 acc = {0.f, 0.f, 0.f, 0.f};
#pragma unroll
        for (int ks = 0; ks < 4; ++ks) {
            bf16x8 afr = *(const bf16x8*)&Wm[(ot * 16 + cr) * 128 + ks * 32 + quad * 8];
            acc = MFMA16(afr, bfr[ks], acc);
        }
        int n = n0 + nt * 16 + cr;
        int o0 = ot * 16 + quad * 4;
#pragma unroll
        for (int r = 0; r < 4; ++r)
            out[((size_t)b * CDIM + o0 + r) * N + n] = acc[r] + bo[o0 + r];
    }
}

// ---------------- launch ----------------
extern "C" void kernel_launch(void* const* d_in, const int* in_sizes, int n_in,
                              void* d_out, int out_size, void* d_ws, size_t ws_size,
                              hipStream_t stream) {
    const float* x  = (const float*)d_in[0];
    const float* wq = (const float*)d_in[1];
    const float* wk = (const float*)d_in[2];
    const float* wv = (const float*)d_in[3];
    const float* wo = (const float*)d_in[4];
    const float* bo = (const float*)d_in[5];

    char* ws = (char*)d_ws;
    bf16* Q = (bf16*)(ws);                       // 4 MB  [bh][n][32]
    bf16* K = (bf16*)(ws + ((size_t)4 << 20));   // 4 MB  [bh][n][32]
    bf16* V = (bf16*)(ws + ((size_t)8 << 20));   // 4 MB  [bh][tile][d32][k64]
    bf16* A = (bf16*)(ws + ((size_t)12 << 20));  // 4 MB  [b][n][128]
    bf16* W = (bf16*)(ws + ((size_t)16 << 20));  // 128 KB

    cvt_w<<<64, 256, 0, stream>>>(wq, wk, wv, wo, W);
    proj_qkv<<<dim3(64, 4, 3), 256, 0, stream>>>(x, W, Q, K, V);
    flash<<<512, 256, 0, stream>>>(Q, K, V, A);
    proj_o<<<dim3(64, 4, 2), 256, 0, stream>>>(A, W, bo, (float*)d_out);
}

// Round 6
// 136.398 us; speedup vs baseline: 1.9098x; 1.1224x over previous
//
#include <hip/hip_runtime.h>
#include <cstdint>

typedef __bf16 bf16;
typedef __bf16 bf16x2 __attribute__((ext_vector_type(2)));
typedef __bf16 bf16x4 __attribute__((ext_vector_type(4)));
typedef __bf16 bf16x8 __attribute__((ext_vector_type(8)));
typedef float f32x4 __attribute__((ext_vector_type(4)));
typedef float f32x16 __attribute__((ext_vector_type(16)));

#define MFMA16(a, b, c) __builtin_amdgcn_mfma_f32_16x16x32_bf16(a, b, c, 0, 0, 0)
#define MFMA32(a, b, c) __builtin_amdgcn_mfma_f32_32x32x16_bf16(a, b, c, 0, 0, 0)

static constexpr int N = 4096;    // 64*64 tokens
static constexpr int CDIM = 128;  // channels
static constexpr int NH = 4;      // heads
static constexpr int DH = 32;     // dim per head

// pack high halves of two f32 (truncate-to-bf16): {bf16(a) lo, bf16(b) hi}
__device__ __forceinline__ uint32_t pack_bf16_trunc(float a, float b) {
    return __builtin_amdgcn_perm(__builtin_bit_cast(uint32_t, b),
                                 __builtin_bit_cast(uint32_t, a), 0x07060302u);
}

__device__ __forceinline__ bf16 to_bf16_rnd(float f) {
    uint32_t u = __builtin_bit_cast(uint32_t, f);
    return __builtin_bit_cast(bf16, (uint16_t)((u + 0x8000u) >> 16));
}

// ---------------- weight convert (fold scale*log2e into wq) ----------------
__global__ __launch_bounds__(256) void cvt_w(const float* __restrict__ wq,
                                             const float* __restrict__ wk,
                                             const float* __restrict__ wv,
                                             const float* __restrict__ wo,
                                             bf16* __restrict__ W) {
    int i = blockIdx.x * 256 + threadIdx.x;  // 0..16383
    const float qs = 0.17677669529663687f * 1.4426950408889634f;  // 32^-0.5 * log2(e)
    W[i]         = (bf16)(wq[i] * qs);
    W[16384 + i] = to_bf16_rnd(wk[i]);
    W[32768 + i] = to_bf16_rnd(wv[i]);
    W[49152 + i] = to_bf16_rnd(wo[i]);
}

// ---------------- QKV projection ----------------
// x: [b][128][4096] f32.  Out: Q,K as [b*4+h][n][32] bf16 ;
// V TILED+PERMUTED: [bh][tile=n>>6][d=32][kperm] bf16, kperm = MFMA-slot order:
// within each 16-key chunk, key groups-of-4 stored as [0-3, 8-11, 4-7, 12-15].
// grid.z = wt (0:Q 1:K 2:V)
__global__ __launch_bounds__(256) void proj_qkv(const float* __restrict__ x,
                                                const bf16* __restrict__ W,
                                                bf16* __restrict__ Q,
                                                bf16* __restrict__ K,
                                                bf16* __restrict__ V) {
    const int b = blockIdx.y;
    const int wt = blockIdx.z;
    const int n0 = blockIdx.x * 64;
    __shared__ __align__(16) bf16 xT[64][136];  // [n][c], padded
    const int tid = threadIdx.x;
    const float* xb = x + (size_t)b * CDIM * N;
    for (int i = tid; i < 64 * 128; i += 256) {
        int n = i & 63, cc = i >> 6;
        xT[n][cc] = to_bf16_rnd(xb[(size_t)cc * N + n0 + n]);
    }
    __syncthreads();

    const int lane = tid & 63, w = tid >> 6;
    const int cr = lane & 15, quad = lane >> 4;

    const bf16* Wm = W + wt * 16384;
    for (int nt = 0; nt < 4; ++nt) {
        bf16x8 bfr[4];
#pragma unroll
        for (int ks = 0; ks < 4; ++ks)
            bfr[ks] = *(const bf16x8*)&xT[nt * 16 + cr][ks * 32 + quad * 8];
#pragma unroll
        for (int ot2 = 0; ot2 < 2; ++ot2) {
            int ot = w * 2 + ot2;
            f32x4 acc = {0.f, 0.f, 0.f, 0.f};
#pragma unroll
            for (int ks = 0; ks < 4; ++ks) {
                bf16x8 afr = *(const bf16x8*)&Wm[(ot * 16 + cr) * 128 + ks * 32 + quad * 8];
                acc = MFMA16(afr, bfr[ks], acc);
            }
            // D: row(o) = ot*16 + quad*4 + r ; col(n) = cr
            int n = n0 + nt * 16 + cr;
            int o0 = ot * 16 + quad * 4;
            if (wt < 2) {
                bf16* dst = (wt == 0) ? Q : K;
                int h = o0 >> 5, d0 = o0 & 31;
                bf16* p = dst + (((size_t)(b * NH + h) * N + n) * DH + d0);
                *(bf16x2*)p       = (bf16x2){(bf16)acc[0], (bf16)acc[1]};
                *(bf16x2*)(p + 2) = (bf16x2){(bf16)acc[2], (bf16)acc[3]};
            } else {
                int h = o0 >> 5, d0 = o0 & 31;
                int k6 = nt * 16 + cr;               // key within 64-tile
                int r4 = (k6 >> 2) & 3;
                int slotgrp = ((r4 & 1) << 1) | (r4 >> 1);  // swap groups 1<->2
                int kperm = (k6 & ~15) | (slotgrp * 4 + (k6 & 3));
                bf16* p = V + ((size_t)(b * NH + h) * 64 + blockIdx.x) * 2048 + kperm;
#pragma unroll
                for (int r = 0; r < 4; ++r)
                    p[(d0 + r) * 64] = (bf16)acc[r];
            }
        }
    }
}

// ---------------- flash attention (32x32 MFMA, no P round-trip) ----------------
// Q,K: [bh][n][32] (wq pre-scaled) ; V tiled+permuted [bh][tile][d32][kperm64].
// O: [b][n][128] bf16. 512 blocks (2/CU), bh = gid&15 (XCD swizzle).
// Block = 128 q (4 waves x 32 q). Per 64-key tile: stage K(4KB)+V(4KB) in LDS.
// S^T via 32x32x16 (C: col=q, row=key); exp2+pack gives PV B-operand directly
// because V's key order is pre-permuted to MFMA slot order.
__global__ __launch_bounds__(256, 2) void flash(const bf16* __restrict__ Q,
                                                const bf16* __restrict__ K,
                                                const bf16* __restrict__ V,
                                                bf16* __restrict__ O) {
    const int gid = blockIdx.x;
    const int bh = gid & 15;
    const int tid = threadIdx.x;
    const int w = tid >> 6, lane = tid & 63;
    const int l31 = lane & 31, h = lane >> 5;
    const int q0w = (gid >> 4) * 128 + w * 32;

    __shared__ __align__(16) bf16 Kl[2][64 * 40];  // rows: key, stride 40
    __shared__ __align__(16) bf16 Vl[2][32 * 72];  // rows: d, stride 72 (kperm cols)

    const bf16* Qb = Q + (size_t)bh * N * DH;
    const bf16* Kb = K + (size_t)bh * N * DH;
    const bf16* Vt = V + (size_t)bh * 64 * 2048;

    const int k_dst = (tid >> 2) * 40 + (tid & 3) * 8;
    const int v_dst = (tid >> 3) * 72 + (tid & 7) * 8;

    // Q B-frags: B[k=d][n=q]: q=lane&31, d=h*8+j (+16 for second frag)
    const bf16x8 qf0 = *(const bf16x8*)&Qb[(q0w + l31) * DH + h * 8];
    const bf16x8 qf1 = *(const bf16x8*)&Qb[(q0w + l31) * DH + 16 + h * 8];

    bf16x8 ones;
#pragma unroll
    for (int i = 0; i < 8; ++i) ones[i] = (bf16)1.0f;

    f32x16 out = {};   // out^T[d=row][q=col]
    f32x16 accL = {};  // all rows = sum_k P (normalizer)

    // preload tile 0
    {
        bf16x8 kreg = *(const bf16x8*)(Kb + tid * 8);
        bf16x8 vreg = *(const bf16x8*)(Vt + tid * 8);
        *(bf16x8*)&Kl[0][k_dst] = kreg;
        *(bf16x8*)&Vl[0][v_dst] = vreg;
    }
    __syncthreads();

    for (int kt = 0; kt < 64; ++kt) {
        const int cb = kt & 1;
        bf16x8 kreg, vreg;
        if (kt < 63) {
            kreg = *(const bf16x8*)(Kb + (kt + 1) * 2048 + tid * 8);
            vreg = *(const bf16x8*)(Vt + (kt + 1) * 2048 + tid * 8);
        }
        const bf16* Kc = &Kl[cb][0];
        const bf16* Vc = &Vl[cb][0];

#pragma unroll
        for (int g2 = 0; g2 < 2; ++g2) {
            // S^T[key][q] for 32 keys: A = K[key=lane&31][d], two d-halves
            bf16x8 kf0 = *(const bf16x8*)&Kc[(g2 * 32 + l31) * 40 + h * 8];
            bf16x8 kf1 = *(const bf16x8*)&Kc[(g2 * 32 + l31) * 40 + 16 + h * 8];
            f32x16 sc = {};
            sc = MFMA32(kf0, qf0, sc);
            sc = MFMA32(kf1, qf1, sc);

            // exp2 + truncate-pack; C row = key = (reg&3)+8*(reg>>2)+4*h
            uint32_t c0 = pack_bf16_trunc(__builtin_amdgcn_exp2f(sc[0]),
                                          __builtin_amdgcn_exp2f(sc[1]));
            uint32_t c1 = pack_bf16_trunc(__builtin_amdgcn_exp2f(sc[2]),
                                          __builtin_amdgcn_exp2f(sc[3]));
            uint32_t c2 = pack_bf16_trunc(__builtin_amdgcn_exp2f(sc[4]),
                                          __builtin_amdgcn_exp2f(sc[5]));
            uint32_t c3 = pack_bf16_trunc(__builtin_amdgcn_exp2f(sc[6]),
                                          __builtin_amdgcn_exp2f(sc[7]));
            uint32_t c4 = pack_bf16_trunc(__builtin_amdgcn_exp2f(sc[8]),
                                          __builtin_amdgcn_exp2f(sc[9]));
            uint32_t c5 = pack_bf16_trunc(__builtin_amdgcn_exp2f(sc[10]),
                                          __builtin_amdgcn_exp2f(sc[11]));
            uint32_t c6 = pack_bf16_trunc(__builtin_amdgcn_exp2f(sc[12]),
                                          __builtin_amdgcn_exp2f(sc[13]));
            uint32_t c7 = pack_bf16_trunc(__builtin_amdgcn_exp2f(sc[14]),
                                          __builtin_amdgcn_exp2f(sc[15]));

            // P^T B-frags: slots h*8..h*8+7 == (c0..c3); +16-key frag == (c4..c7)
            // (valid because V's key order is permuted to match C-row ownership)
            bf16x8 pB0, pB1;
            {
                uint32_t t0[4] = {c0, c1, c2, c3};
                uint32_t t1[4] = {c4, c5, c6, c7};
                pB0 = *(bf16x8*)t0;
                pB1 = *(bf16x8*)t1;
            }

            // PV: out^T[d][q] += V^T[d][slot] * P^T[slot][q]
            bf16x8 av0 = *(const bf16x8*)&Vc[l31 * 72 + g2 * 32 + h * 8];
            bf16x8 av1 = *(const bf16x8*)&Vc[l31 * 72 + g2 * 32 + 16 + h * 8];
            out = MFMA32(av0, pB0, out);
            out = MFMA32(av1, pB1, out);
            accL = MFMA32(ones, pB0, accL);
            accL = MFMA32(ones, pB1, accL);
        }

        if (kt < 63) {
            *(bf16x8*)&Kl[1 - cb][k_dst] = kreg;
            *(bf16x8*)&Vl[1 - cb][v_dst] = vreg;
        }
        __syncthreads();
    }

    const float inv = __builtin_amdgcn_rcpf(accL[0]);
    const int b = bh >> 2, hh = bh & 3;
    bf16* Ob = O + ((size_t)b * N + q0w + l31) * CDIM + hh * DH;
#pragma unroll
    for (int rg = 0; rg < 4; ++rg) {
        const int d0 = rg * 8 + h * 4;  // C rows: (reg&3)+8*(reg>>2)+4*h
        bf16x4 v = {(bf16)(out[rg * 4 + 0] * inv), (bf16)(out[rg * 4 + 1] * inv),
                    (bf16)(out[rg * 4 + 2] * inv), (bf16)(out[rg * 4 + 3] * inv)};
        *(bf16x4*)(Ob + d0) = v;
    }
}

// ---------------- output projection ----------------
// A: [b][n][128] bf16 ; out: [b][128][4096] f32 with bias. grid.z splits ot.
__global__ __launch_bounds__(256) void proj_o(const bf16* __restrict__ A,
                                              const bf16* __restrict__ W,
                                              const float* __restrict__ bo,
                                              float* __restrict__ out) {
    const int b = blockIdx.y;
    const int n0 = blockIdx.x * 64;
    __shared__ __align__(16) bf16 aT[64][136];  // [n][c]
    const int tid = threadIdx.x;
    const bf16* Ab = A + (size_t)b * N * CDIM;
    for (int i = tid; i < 64 * 64; i += 256) {
        int c2 = i & 63, n = i >> 6;
        *(uint32_t*)&aT[n][c2 * 2] = *(const uint32_t*)&Ab[(size_t)(n0 + n) * CDIM + c2 * 2];
    }
    __syncthreads();

    const int lane = tid & 63, w = tid >> 6;
    const int cr = lane & 15, quad = lane >> 4;
    const bf16* Wm = W + 3 * 16384;  // wo
    const int ot = blockIdx.z * 4 + w;

    for (int nt = 0; nt < 4; ++nt) {
        bf16x8 bfr[4];
#pragma unroll
        for (int ks = 0; ks < 4; ++ks)
            bfr[ks] = *(const bf16x8*)&aT[nt * 16 + cr][ks * 32 + quad * 8];
        f32x4 acc = {0.f, 0.f, 0.f, 0.f};
#pragma unroll
        for (int ks = 0; ks < 4; ++ks) {
            bf16x8 afr = *(const bf16x8*)&Wm[(ot * 16 + cr) * 128 + ks * 32 + quad * 8];
            acc = MFMA16(afr, bfr[ks], acc);
        }
        int n = n0 + nt * 16 + cr;
        int o0 = ot * 16 + quad * 4;
#pragma unroll
        for (int r = 0; r < 4; ++r)
            out[((size_t)b * CDIM + o0 + r) * N + n] = acc[r] + bo[o0 + r];
    }
}

// ---------------- launch ----------------
extern "C" void kernel_launch(void* const* d_in, const int* in_sizes, int n_in,
                              void* d_out, int out_size, void* d_ws, size_t ws_size,
                              hipStream_t stream) {
    const float* x  = (const float*)d_in[0];
    const float* wq = (const float*)d_in[1];
    const float* wk = (const float*)d_in[2];
    const float* wv = (const float*)d_in[3];
    const float* wo = (const float*)d_in[4];
    const float* bo = (const float*)d_in[5];

    char* ws = (char*)d_ws;
    bf16* Q = (bf16*)(ws);                       // 4 MB  [bh][n][32]
    bf16* K = (bf16*)(ws + ((size_t)4 << 20));   // 4 MB  [bh][n][32]
    bf16* V = (bf16*)(ws + ((size_t)8 << 20));   // 4 MB  [bh][tile][d32][kperm64]
    bf16* A = (bf16*)(ws + ((size_t)12 << 20));  // 4 MB  [b][n][128]
    bf16* W = (bf16*)(ws + ((size_t)16 << 20));  // 128 KB

    cvt_w<<<64, 256, 0, stream>>>(wq, wk, wv, wo, W);
    proj_qkv<<<dim3(64, 4, 3), 256, 0, stream>>>(x, W, Q, K, V);
    flash<<<512, 256, 0, stream>>>(Q, K, V, A);
    proj_o<<<dim3(64, 4, 2), 256, 0, stream>>>(A, W, bo, (float*)d_out);
}

// Round 7
// 132.392 us; speedup vs baseline: 1.9676x; 1.0303x over previous
//
#include <hip/hip_runtime.h>
#include <cstdint>

typedef __bf16 bf16;
typedef __bf16 bf16x2 __attribute__((ext_vector_type(2)));
typedef __bf16 bf16x4 __attribute__((ext_vector_type(4)));
typedef __bf16 bf16x8 __attribute__((ext_vector_type(8)));
typedef float f32x4 __attribute__((ext_vector_type(4)));
typedef float f32x16 __attribute__((ext_vector_type(16)));

#define MFMA16(a, b, c) __builtin_amdgcn_mfma_f32_16x16x32_bf16(a, b, c, 0, 0, 0)
#define MFMA32(a, b, c) __builtin_amdgcn_mfma_f32_32x32x16_bf16(a, b, c, 0, 0, 0)

static constexpr int N = 4096;    // 64*64 tokens
static constexpr int CDIM = 128;  // channels
static constexpr int NH = 4;      // heads
static constexpr int DH = 32;     // dim per head

// pack high halves of two f32 (truncate-to-bf16): {bf16(a) lo, bf16(b) hi}
__device__ __forceinline__ uint32_t pack_bf16_trunc(float a, float b) {
    return __builtin_amdgcn_perm(__builtin_bit_cast(uint32_t, b),
                                 __builtin_bit_cast(uint32_t, a), 0x07060302u);
}

__device__ __forceinline__ bf16 to_bf16_rnd(float f) {
    uint32_t u = __builtin_bit_cast(uint32_t, f);
    return __builtin_bit_cast(bf16, (uint16_t)((u + 0x8000u) >> 16));
}

// ---------------- weight convert (fold scale*log2e into wq) ----------------
__global__ __launch_bounds__(256) void cvt_w(const float* __restrict__ wq,
                                             const float* __restrict__ wk,
                                             const float* __restrict__ wv,
                                             const float* __restrict__ wo,
                                             bf16* __restrict__ W) {
    int i = blockIdx.x * 256 + threadIdx.x;  // 0..16383
    const float qs = 0.17677669529663687f * 1.4426950408889634f;  // 32^-0.5 * log2(e)
    W[i]         = (bf16)(wq[i] * qs);
    W[16384 + i] = to_bf16_rnd(wk[i]);
    W[32768 + i] = to_bf16_rnd(wv[i]);
    W[49152 + i] = to_bf16_rnd(wo[i]);
}

// ---------------- QKV projection ----------------
// x: [b][128][4096] f32.  Out: Q,K as [b*4+h][n][32] bf16 ;
// V TILED+PERMUTED: [bh][tile=n>>6][d=32][kperm] bf16, kperm = MFMA-slot order.
// grid.z = wt (0:Q 1:K 2:V)
__global__ __launch_bounds__(256) void proj_qkv(const float* __restrict__ x,
                                                const bf16* __restrict__ W,
                                                bf16* __restrict__ Q,
                                                bf16* __restrict__ K,
                                                bf16* __restrict__ V) {
    const int b = blockIdx.y;
    const int wt = blockIdx.z;
    const int n0 = blockIdx.x * 64;
    __shared__ __align__(16) bf16 xT[64][136];  // [n][c], padded
    const int tid = threadIdx.x;
    const float* xb = x + (size_t)b * CDIM * N;
    for (int i = tid; i < 64 * 32; i += 256) {  // 8 float4 per thread
        int n4 = (i & 15) * 4, cc = i >> 4;
        const float4 v = *(const float4*)&xb[(size_t)cc * N + n0 + n4];
        xT[n4 + 0][cc] = to_bf16_rnd(v.x);
        xT[n4 + 1][cc] = to_bf16_rnd(v.y);
        xT[n4 + 2][cc] = to_bf16_rnd(v.z);
        xT[n4 + 3][cc] = to_bf16_rnd(v.w);
    }
    __syncthreads();

    const int lane = tid & 63, w = tid >> 6;
    const int cr = lane & 15, quad = lane >> 4;

    const bf16* Wm = W + wt * 16384;
    for (int nt = 0; nt < 4; ++nt) {
        bf16x8 bfr[4];
#pragma unroll
        for (int ks = 0; ks < 4; ++ks)
            bfr[ks] = *(const bf16x8*)&xT[nt * 16 + cr][ks * 32 + quad * 8];
#pragma unroll
        for (int ot2 = 0; ot2 < 2; ++ot2) {
            int ot = w * 2 + ot2;
            f32x4 acc = {0.f, 0.f, 0.f, 0.f};
#pragma unroll
            for (int ks = 0; ks < 4; ++ks) {
                bf16x8 afr = *(const bf16x8*)&Wm[(ot * 16 + cr) * 128 + ks * 32 + quad * 8];
                acc = MFMA16(afr, bfr[ks], acc);
            }
            // D: row(o) = ot*16 + quad*4 + r ; col(n) = cr
            int n = n0 + nt * 16 + cr;
            int o0 = ot * 16 + quad * 4;
            if (wt < 2) {
                bf16* dst = (wt == 0) ? Q : K;
                int h = o0 >> 5, d0 = o0 & 31;
                bf16* p = dst + (((size_t)(b * NH + h) * N + n) * DH + d0);
                *(bf16x2*)p       = (bf16x2){(bf16)acc[0], (bf16)acc[1]};
                *(bf16x2*)(p + 2) = (bf16x2){(bf16)acc[2], (bf16)acc[3]};
            } else {
                int h = o0 >> 5, d0 = o0 & 31;
                int k6 = nt * 16 + cr;               // key within 64-tile
                int r4 = (k6 >> 2) & 3;
                int slotgrp = ((r4 & 1) << 1) | (r4 >> 1);  // swap groups 1<->2
                int kperm = (k6 & ~15) | (slotgrp * 4 + (k6 & 3));
                bf16* p = V + ((size_t)(b * NH + h) * 64 + blockIdx.x) * 2048 + kperm;
#pragma unroll
                for (int r = 0; r < 4; ++r)
                    p[(d0 + r) * 64] = (bf16)acc[r];
            }
        }
    }
}

// ---------------- flash attention (64q/wave + intra-block split-K x2) ----------------
// Q,K: [bh][n][32] (wq pre-scaled) ; V tiled+permuted [bh][tile][d32][kperm64].
// O: [b][n][128] bf16. 512 blocks (2/CU), bh = gid&15 (XCD swizzle).
// Block = 256 q; wave w: q-group qg=w>>1 (64 q), key-half kh=w&1 (32 of 64 tiles).
// No running max => K-half partials (O, l) combine by plain addition via LDS.
__global__ __launch_bounds__(256, 2) void flash(const bf16* __restrict__ Q,
                                                const bf16* __restrict__ K,
                                                const bf16* __restrict__ V,
                                                bf16* __restrict__ O) {
    const int gid = blockIdx.x;
    const int bh = gid & 15;
    const int qblk = gid >> 4;  // 0..31
    const int tid = threadIdx.x;
    const int w = tid >> 6, lane = tid & 63;
    const int l31 = lane & 31, h = lane >> 5;
    const int qg = w >> 1, kh = w & 1;
    const int qbase = qblk * 128 + qg * 64;

    __shared__ __align__(16) bf16 Kl[2][2][64 * 40];  // [buf][half], 20480 B
    __shared__ __align__(16) bf16 Vl[2][2][32 * 72];  // [buf][half], 18432 B

    const bf16* Qb = Q + (size_t)bh * N * DH;
    const bf16* Kb = K + (size_t)bh * N * DH;
    const bf16* Vt = V + (size_t)bh * 64 * 2048;

    const bf16* ksrc0 = Kb + tid * 8;            // half0 tiles 0..31
    const bf16* ksrc1 = Kb + 65536 + tid * 8;    // half1 tiles 32..63
    const bf16* vsrc0 = Vt + tid * 8;
    const bf16* vsrc1 = Vt + 65536 + tid * 8;
    const int k_dst = (tid >> 2) * 40 + (tid & 3) * 8;
    const int v_dst = (tid >> 3) * 72 + (tid & 7) * 8;

    bf16x8 qf[2][2];  // [qs][d-half]
#pragma unroll
    for (int qs = 0; qs < 2; ++qs)
#pragma unroll
        for (int dh = 0; dh < 2; ++dh)
            qf[qs][dh] = *(const bf16x8*)&Qb[(qbase + qs * 32 + l31) * DH + dh * 16 + h * 8];

    bf16x8 ones;
#pragma unroll
    for (int i = 0; i < 8; ++i) ones[i] = (bf16)1.0f;

    f32x16 out[2] = {};   // [qs]: out^T[d=row][q=col]
    f32x16 accL[2] = {};  // [qs]: normalizer rows (all equal)

    // preload tile 0 of both halves
    *(bf16x8*)&Kl[0][0][k_dst] = *(const bf16x8*)ksrc0;
    *(bf16x8*)&Kl[0][1][k_dst] = *(const bf16x8*)ksrc1;
    *(bf16x8*)&Vl[0][0][v_dst] = *(const bf16x8*)vsrc0;
    *(bf16x8*)&Vl[0][1][v_dst] = *(const bf16x8*)vsrc1;
    __syncthreads();

    for (int kt = 0; kt < 32; ++kt) {
        const int cb = kt & 1;
        bf16x8 pk0, pk1, pv0, pv1;
        if (kt < 31) {
            pk0 = *(const bf16x8*)(ksrc0 + (kt + 1) * 2048);
            pk1 = *(const bf16x8*)(ksrc1 + (kt + 1) * 2048);
            pv0 = *(const bf16x8*)(vsrc0 + (kt + 1) * 2048);
            pv1 = *(const bf16x8*)(vsrc1 + (kt + 1) * 2048);
        }
        const bf16* Kc = &Kl[cb][kh][0];
        const bf16* Vc = &Vl[cb][kh][0];

#pragma unroll
        for (int g2 = 0; g2 < 2; ++g2) {
            bf16x8 kf0 = *(const bf16x8*)&Kc[(g2 * 32 + l31) * 40 + h * 8];
            bf16x8 kf1 = *(const bf16x8*)&Kc[(g2 * 32 + l31) * 40 + 16 + h * 8];
            bf16x8 av0 = *(const bf16x8*)&Vc[l31 * 72 + g2 * 32 + h * 8];
            bf16x8 av1 = *(const bf16x8*)&Vc[l31 * 72 + g2 * 32 + 16 + h * 8];
#pragma unroll
            for (int qs = 0; qs < 2; ++qs) {
                f32x16 sc = {};
                sc = MFMA32(kf0, qf[qs][0], sc);
                sc = MFMA32(kf1, qf[qs][1], sc);

                uint32_t c0 = pack_bf16_trunc(__builtin_amdgcn_exp2f(sc[0]),
                                              __builtin_amdgcn_exp2f(sc[1]));
                uint32_t c1 = pack_bf16_trunc(__builtin_amdgcn_exp2f(sc[2]),
                                              __builtin_amdgcn_exp2f(sc[3]));
                uint32_t c2 = pack_bf16_trunc(__builtin_amdgcn_exp2f(sc[4]),
                                              __builtin_amdgcn_exp2f(sc[5]));
                uint32_t c3 = pack_bf16_trunc(__builtin_amdgcn_exp2f(sc[6]),
                                              __builtin_amdgcn_exp2f(sc[7]));
                uint32_t c4 = pack_bf16_trunc(__builtin_amdgcn_exp2f(sc[8]),
                                              __builtin_amdgcn_exp2f(sc[9]));
                uint32_t c5 = pack_bf16_trunc(__builtin_amdgcn_exp2f(sc[10]),
                                              __builtin_amdgcn_exp2f(sc[11]));
                uint32_t c6 = pack_bf16_trunc(__builtin_amdgcn_exp2f(sc[12]),
                                              __builtin_amdgcn_exp2f(sc[13]));
                uint32_t c7 = pack_bf16_trunc(__builtin_amdgcn_exp2f(sc[14]),
                                              __builtin_amdgcn_exp2f(sc[15]));

                bf16x8 pB0, pB1;
                {
                    uint32_t t0[4] = {c0, c1, c2, c3};
                    uint32_t t1[4] = {c4, c5, c6, c7};
                    pB0 = *(bf16x8*)t0;
                    pB1 = *(bf16x8*)t1;
                }

                out[qs]  = MFMA32(av0, pB0, out[qs]);
                out[qs]  = MFMA32(av1, pB1, out[qs]);
                accL[qs] = MFMA32(ones, pB0, accL[qs]);
                accL[qs] = MFMA32(ones, pB1, accL[qs]);
            }
        }

        if (kt < 31) {
            *(bf16x8*)&Kl[1 - cb][0][k_dst] = pk0;
            *(bf16x8*)&Kl[1 - cb][1][k_dst] = pk1;
            *(bf16x8*)&Vl[1 - cb][0][v_dst] = pv0;
            *(bf16x8*)&Vl[1 - cb][1][v_dst] = pv1;
        }
        __syncthreads();
    }

    // combine the two key-halves (plain addition): overlay reduction on Kl
    float* red = (float*)&Kl[0][0][0];  // [qg*2+qs][lane][20] f32 = 20480 B
    if (kh == 1) {
#pragma unroll
        for (int qs = 0; qs < 2; ++qs) {
            float* r = red + ((size_t)((qg * 2 + qs) * 64 + lane)) * 20;
            f32x4 t0 = {out[qs][0], out[qs][1], out[qs][2], out[qs][3]};
            f32x4 t1 = {out[qs][4], out[qs][5], out[qs][6], out[qs][7]};
            f32x4 t2 = {out[qs][8], out[qs][9], out[qs][10], out[qs][11]};
            f32x4 t3 = {out[qs][12], out[qs][13], out[qs][14], out[qs][15]};
            *(f32x4*)(r + 0)  = t0;
            *(f32x4*)(r + 4)  = t1;
            *(f32x4*)(r + 8)  = t2;
            *(f32x4*)(r + 12) = t3;
            r[16] = accL[qs][0];
        }
    }
    __syncthreads();
    if (kh == 0) {
        const int b = bh >> 2, hh = bh & 3;
#pragma unroll
        for (int qs = 0; qs < 2; ++qs) {
            const float* r = red + ((size_t)((qg * 2 + qs) * 64 + lane)) * 20;
#pragma unroll
            for (int i = 0; i < 16; ++i) out[qs][i] += r[i];
            float inv = __builtin_amdgcn_rcpf(accL[qs][0] + r[16]);
            bf16* Ob = O + ((size_t)b * N + qbase + qs * 32 + l31) * CDIM + hh * DH;
#pragma unroll
            for (int rg = 0; rg < 4; ++rg) {
                const int d0 = rg * 8 + h * 4;  // C rows: (reg&3)+8*(reg>>2)+4*h
                bf16x4 v = {(bf16)(out[qs][rg * 4 + 0] * inv), (bf16)(out[qs][rg * 4 + 1] * inv),
                            (bf16)(out[qs][rg * 4 + 2] * inv), (bf16)(out[qs][rg * 4 + 3] * inv)};
                *(bf16x4*)(Ob + d0) = v;
            }
        }
    }
}

// ---------------- output projection ----------------
// A: [b][n][128] bf16 ; out: [b][128][4096] f32 with bias. grid.z splits ot.
__global__ __launch_bounds__(256) void proj_o(const bf16* __restrict__ A,
                                              const bf16* __restrict__ W,
                                              const float* __restrict__ bo,
                                              float* __restrict__ out) {
    const int b = blockIdx.y;
    const int n0 = blockIdx.x * 64;
    __shared__ __align__(16) bf16 aT[64][136];  // [n][c]
    const int tid = threadIdx.x;
    const bf16* Ab = A + (size_t)b * N * CDIM;
    for (int i = tid; i < 64 * 16; i += 256) {  // 4 b128 copies per thread
        int c8 = (i & 15) * 8, n = i >> 4;
        *(bf16x8*)&aT[n][c8] = *(const bf16x8*)&Ab[(size_t)(n0 + n) * CDIM + c8];
    }
    __syncthreads();

    const int lane = tid & 63, w = tid >> 6;
    const int cr = lane & 15, quad = lane >> 4;
    const bf16* Wm = W + 3 * 16384;  // wo
    const int ot = blockIdx.z * 4 + w;

    for (int nt = 0; nt < 4; ++nt) {
        bf16x8 bfr[4];
#pragma unroll
        for (int ks = 0; ks < 4; ++ks)
            bfr[ks] = *(const bf16x8*)&aT[nt * 16 + cr][ks * 32 + quad * 8];
        f32x4 acc = {0.f, 0.f, 0.f, 0.f};
#pragma unroll
        for (int ks = 0; ks < 4; ++ks) {
            bf16x8 afr = *(const bf16x8*)&Wm[(ot * 16 + cr) * 128 + ks * 32 + quad * 8];
            acc = MFMA16(afr, bfr[ks], acc);
        }
        int n = n0 + nt * 16 + cr;
        int o0 = ot * 16 + quad * 4;
#pragma unroll
        for (int r = 0; r < 4; ++r)
            out[((size_t)b * CDIM + o0 + r) * N + n] = acc[r] + bo[o0 + r];
    }
}

// ---------------- launch ----------------
extern "C" void kernel_launch(void* const* d_in, const int* in_sizes, int n_in,
                              void* d_out, int out_size, void* d_ws, size_t ws_size,
                              hipStream_t stream) {
    const float* x  = (const float*)d_in[0];
    const float* wq = (const float*)d_in[1];
    const float* wk = (const float*)d_in[2];
    const float* wv = (const float*)d_in[3];
    const float* wo = (const float*)d_in[4];
    const float* bo = (const float*)d_in[5];

    char* ws = (char*)d_ws;
    bf16* Q = (bf16*)(ws);                       // 4 MB  [bh][n][32]
    bf16* K = (bf16*)(ws + ((size_t)4 << 20));   // 4 MB  [bh][n][32]
    bf16* V = (bf16*)(ws + ((size_t)8 << 20));   // 4 MB  [bh][tile][d32][kperm64]
    bf16* A = (bf16*)(ws + ((size_t)12 << 20));  // 4 MB  [b][n][128]
    bf16* W = (bf16*)(ws + ((size_t)16 << 20));  // 128 KB

    cvt_w<<<64, 256, 0, stream>>>(wq, wk, wv, wo, W);
    proj_qkv<<<dim3(64, 4, 3), 256, 0, stream>>>(x, W, Q, K, V);
    flash<<<512, 256, 0, stream>>>(Q, K, V, A);
    proj_o<<<dim3(64, 4, 2), 256, 0, stream>>>(A, W, bo, (float*)d_out);
}

// Round 8
// 131.755 us; speedup vs baseline: 1.9771x; 1.0048x over previous
//
#include <hip/hip_runtime.h>
#include <cstdint>

typedef __bf16 bf16;
typedef __bf16 bf16x2 __attribute__((ext_vector_type(2)));
typedef __bf16 bf16x4 __attribute__((ext_vector_type(4)));
typedef __bf16 bf16x8 __attribute__((ext_vector_type(8)));
typedef float f32x4 __attribute__((ext_vector_type(4)));
typedef float f32x16 __attribute__((ext_vector_type(16)));

#define MFMA16(a, b, c) __builtin_amdgcn_mfma_f32_16x16x32_bf16(a, b, c, 0, 0, 0)
#define MFMA32(a, b, c) __builtin_amdgcn_mfma_f32_32x32x16_bf16(a, b, c, 0, 0, 0)

static constexpr int N = 4096;    // 64*64 tokens
static constexpr int CDIM = 128;  // channels
static constexpr int NH = 4;      // heads
static constexpr int DH = 32;     // dim per head

// pack high halves of two f32 (truncate-to-bf16): {bf16(a) lo, bf16(b) hi}
__device__ __forceinline__ uint32_t pack_bf16_trunc(float a, float b) {
    return __builtin_amdgcn_perm(__builtin_bit_cast(uint32_t, b),
                                 __builtin_bit_cast(uint32_t, a), 0x07060302u);
}

__device__ __forceinline__ bf16 to_bf16_rnd(float f) {
    uint32_t u = __builtin_bit_cast(uint32_t, f);
    return __builtin_bit_cast(bf16, (uint16_t)((u + 0x8000u) >> 16));
}

// ---------------- weight convert (fold scale*log2e into wq) ----------------
__global__ __launch_bounds__(256) void cvt_w(const float* __restrict__ wq,
                                             const float* __restrict__ wk,
                                             const float* __restrict__ wv,
                                             const float* __restrict__ wo,
                                             bf16* __restrict__ W) {
    int i = blockIdx.x * 256 + threadIdx.x;  // 0..16383
    const float qs = 0.17677669529663687f * 1.4426950408889634f;  // 32^-0.5 * log2(e)
    W[i]         = (bf16)(wq[i] * qs);
    W[16384 + i] = to_bf16_rnd(wk[i]);
    W[32768 + i] = to_bf16_rnd(wv[i]);
    W[49152 + i] = to_bf16_rnd(wo[i]);
}

// ---------------- QKV projection ----------------
// x: [b][128][4096] f32.  Out: Q,K as [b*4+h][n][32] bf16 ;
// V TILED+PERMUTED: [bh][tile=n>>6][d=32][kperm] bf16, kperm = MFMA-slot order.
// grid.z = wt (0:Q 1:K 2:V)
__global__ __launch_bounds__(256) void proj_qkv(const float* __restrict__ x,
                                                const bf16* __restrict__ W,
                                                bf16* __restrict__ Q,
                                                bf16* __restrict__ K,
                                                bf16* __restrict__ V) {
    const int b = blockIdx.y;
    const int wt = blockIdx.z;
    const int n0 = blockIdx.x * 64;
    __shared__ __align__(16) bf16 xT[64][136];  // [n][c], padded
    const int tid = threadIdx.x;
    const float* xb = x + (size_t)b * CDIM * N;
    for (int i = tid; i < 64 * 32; i += 256) {  // 8 float4 per thread
        int n4 = (i & 15) * 4, cc = i >> 4;
        const float4 v = *(const float4*)&xb[(size_t)cc * N + n0 + n4];
        xT[n4 + 0][cc] = to_bf16_rnd(v.x);
        xT[n4 + 1][cc] = to_bf16_rnd(v.y);
        xT[n4 + 2][cc] = to_bf16_rnd(v.z);
        xT[n4 + 3][cc] = to_bf16_rnd(v.w);
    }
    __syncthreads();

    const int lane = tid & 63, w = tid >> 6;
    const int cr = lane & 15, quad = lane >> 4;

    const bf16* Wm = W + wt * 16384;
    for (int nt = 0; nt < 4; ++nt) {
        bf16x8 bfr[4];
#pragma unroll
        for (int ks = 0; ks < 4; ++ks)
            bfr[ks] = *(const bf16x8*)&xT[nt * 16 + cr][ks * 32 + quad * 8];
#pragma unroll
        for (int ot2 = 0; ot2 < 2; ++ot2) {
            int ot = w * 2 + ot2;
            f32x4 acc = {0.f, 0.f, 0.f, 0.f};
#pragma unroll
            for (int ks = 0; ks < 4; ++ks) {
                bf16x8 afr = *(const bf16x8*)&Wm[(ot * 16 + cr) * 128 + ks * 32 + quad * 8];
                acc = MFMA16(afr, bfr[ks], acc);
            }
            // D: row(o) = ot*16 + quad*4 + r ; col(n) = cr
            int n = n0 + nt * 16 + cr;
            int o0 = ot * 16 + quad * 4;
            if (wt < 2) {
                bf16* dst = (wt == 0) ? Q : K;
                int h = o0 >> 5, d0 = o0 & 31;
                bf16* p = dst + (((size_t)(b * NH + h) * N + n) * DH + d0);
                *(bf16x2*)p       = (bf16x2){(bf16)acc[0], (bf16)acc[1]};
                *(bf16x2*)(p + 2) = (bf16x2){(bf16)acc[2], (bf16)acc[3]};
            } else {
                int h = o0 >> 5, d0 = o0 & 31;
                int k6 = nt * 16 + cr;               // key within 64-tile
                int r4 = (k6 >> 2) & 3;
                int slotgrp = ((r4 & 1) << 1) | (r4 >> 1);  // swap groups 1<->2
                int kperm = (k6 & ~15) | (slotgrp * 4 + (k6 & 3));
                bf16* p = V + ((size_t)(b * NH + h) * 64 + blockIdx.x) * 2048 + kperm;
#pragma unroll
                for (int r = 0; r < 4; ++r)
                    p[(d0 + r) * 64] = (bf16)acc[r];
            }
        }
    }
}

// ---------------- flash attention (512 thr: 2 qg x 4-way split-K) ----------------
// Q,K: [bh][n][32] (wq pre-scaled) ; V tiled+permuted [bh][tile][d32][kperm64].
// O: [b][n][128] bf16. 512 blocks (2/CU), bh = gid&15 (XCD swizzle).
// Block = 128 q over 8 waves: wave w -> qg = w&1 (64 q), kh = w>>1 (K quarter,
// 16 tiles of 64 keys). Single-buffered LDS staging of all 4 quarter tiles,
// register prefetch across the compute phase. No running max => kh partials
// (O, l) combine by plain addition via LDS overlay.
// Normalizer trick: one f32x16 accL holds both qs sums: A1 = ones on rows 0-7
// (l_qs0 -> accL[0]), A2 = ones on rows 8-15 (l_qs1 -> accL[4]).
__global__ __launch_bounds__(512, 4) void flash(const bf16* __restrict__ Q,
                                                const bf16* __restrict__ K,
                                                const bf16* __restrict__ V,
                                                bf16* __restrict__ O) {
    const int gid = blockIdx.x;
    const int bh = gid & 15;
    const int qblk = gid >> 4;  // 0..31
    const int tid = threadIdx.x;
    const int w = tid >> 6, lane = tid & 63;
    const int l31 = lane & 31, h = lane >> 5;
    const int qg = w & 1, kh = w >> 1;
    const int qbase = qblk * 128 + qg * 64;

    __shared__ __align__(16) bf16 Kl[4][64 * 40];  // 20480 B, key rows stride 40
    __shared__ __align__(16) bf16 Vl[4][32 * 72];  // 18432 B, d rows stride 72

    const bf16* Qb = Q + (size_t)bh * N * DH;
    const bf16* Kb = K + (size_t)bh * N * DH;
    const bf16* Vt = V + (size_t)bh * 64 * 2048;

    // staging: quarter qtr = tid>>7, within-quarter t = tid&127; 2x16B K + 2x16B V
    const int qtr = tid >> 7, t = tid & 127;
    const bf16* ksrc = Kb + (size_t)(qtr * 16) * 2048 + t * 16;
    const bf16* vsrc = Vt + (size_t)(qtr * 16) * 2048 + t * 16;
    bf16* kdst = &Kl[qtr][(t >> 1) * 40 + (t & 1) * 16];
    bf16* vdst = &Vl[qtr][(t >> 2) * 72 + (t & 3) * 16];

    bf16x8 qf[2][2];  // [qs][d-half]
#pragma unroll
    for (int qs = 0; qs < 2; ++qs)
#pragma unroll
        for (int dh = 0; dh < 2; ++dh)
            qf[qs][dh] = *(const bf16x8*)&Qb[(qbase + qs * 32 + l31) * DH + dh * 16 + h * 8];

    bf16x8 A1, A2;  // masked-ones A operands for the normalizer MFMA
    {
        bf16 one = (bf16)1.0f, zero = (bf16)0.0f;
        bf16 v1 = (l31 < 8) ? one : zero;
        bf16 v2 = (l31 >= 8 && l31 < 16) ? one : zero;
#pragma unroll
        for (int i = 0; i < 8; ++i) { A1[i] = v1; A2[i] = v2; }
    }

    f32x16 out[2] = {};  // [qs]: out^T[d=row][q=col]
    f32x16 accL = {};    // rows 0-7: l_qs0 ; rows 8-15: l_qs1

    // prefetch tile 0
    bf16x8 kr0 = *(const bf16x8*)(ksrc);
    bf16x8 kr1 = *(const bf16x8*)(ksrc + 8);
    bf16x8 vr0 = *(const bf16x8*)(vsrc);
    bf16x8 vr1 = *(const bf16x8*)(vsrc + 8);

    for (int kt = 0; kt < 16; ++kt) {
        __syncthreads();  // consumers of previous tile done
        *(bf16x8*)(kdst)     = kr0;
        *(bf16x8*)(kdst + 8) = kr1;
        *(bf16x8*)(vdst)     = vr0;
        *(bf16x8*)(vdst + 8) = vr1;
        __syncthreads();  // tile staged
        if (kt < 15) {
            const size_t off = (size_t)(kt + 1) * 2048;
            kr0 = *(const bf16x8*)(ksrc + off);
            kr1 = *(const bf16x8*)(ksrc + off + 8);
            vr0 = *(const bf16x8*)(vsrc + off);
            vr1 = *(const bf16x8*)(vsrc + off + 8);
        }
        const bf16* Kc = &Kl[kh][0];
        const bf16* Vc = &Vl[kh][0];

#pragma unroll
        for (int g2 = 0; g2 < 2; ++g2) {
            bf16x8 kf0 = *(const bf16x8*)&Kc[(g2 * 32 + l31) * 40 + h * 8];
            bf16x8 kf1 = *(const bf16x8*)&Kc[(g2 * 32 + l31) * 40 + 16 + h * 8];
            bf16x8 av0 = *(const bf16x8*)&Vc[l31 * 72 + g2 * 32 + h * 8];
            bf16x8 av1 = *(const bf16x8*)&Vc[l31 * 72 + g2 * 32 + 16 + h * 8];
#pragma unroll
            for (int qs = 0; qs < 2; ++qs) {
                f32x16 sc = {};
                sc = MFMA32(kf0, qf[qs][0], sc);
                sc = MFMA32(kf1, qf[qs][1], sc);

                uint32_t c0 = pack_bf16_trunc(__builtin_amdgcn_exp2f(sc[0]),
                                              __builtin_amdgcn_exp2f(sc[1]));
                uint32_t c1 = pack_bf16_trunc(__builtin_amdgcn_exp2f(sc[2]),
                                              __builtin_amdgcn_exp2f(sc[3]));
                uint32_t c2 = pack_bf16_trunc(__builtin_amdgcn_exp2f(sc[4]),
                                              __builtin_amdgcn_exp2f(sc[5]));
                uint32_t c3 = pack_bf16_trunc(__builtin_amdgcn_exp2f(sc[6]),
                                              __builtin_amdgcn_exp2f(sc[7]));
                uint32_t c4 = pack_bf16_trunc(__builtin_amdgcn_exp2f(sc[8]),
                                              __builtin_amdgcn_exp2f(sc[9]));
                uint32_t c5 = pack_bf16_trunc(__builtin_amdgcn_exp2f(sc[10]),
                                              __builtin_amdgcn_exp2f(sc[11]));
                uint32_t c6 = pack_bf16_trunc(__builtin_amdgcn_exp2f(sc[12]),
                                              __builtin_amdgcn_exp2f(sc[13]));
                uint32_t c7 = pack_bf16_trunc(__builtin_amdgcn_exp2f(sc[14]),
                                              __builtin_amdgcn_exp2f(sc[15]));

                bf16x8 pB0, pB1;
                {
                    uint32_t t0[4] = {c0, c1, c2, c3};
                    uint32_t t1[4] = {c4, c5, c6, c7};
                    pB0 = *(bf16x8*)t0;
                    pB1 = *(bf16x8*)t1;
                }

                out[qs] = MFMA32(av0, pB0, out[qs]);
                out[qs] = MFMA32(av1, pB1, out[qs]);
                const bf16x8 Am = qs ? A2 : A1;
                accL = MFMA32(Am, pB0, accL);
                accL = MFMA32(Am, pB1, accL);
            }
        }
    }

    // 4-way kh combine (plain addition), one qs per round; overlay on Kl/Vl.
    // Per-lane record: 16 out + 1 l, stride 20 f32 (16B aligned).
    float* red = (float*)&Kl[0][0];  // 6*64*20*4 = 30720 B <= 38912 B
    const int b = bh >> 2, hh = bh & 3;
#pragma unroll
    for (int qs = 0; qs < 2; ++qs) {
        const float myL = qs ? accL[4] : accL[0];
        __syncthreads();
        if (kh > 0) {
            float* r = red + (((kh - 1) * 2 + qg) * 64 + lane) * 20;
            *(f32x4*)(r + 0)  = (f32x4){out[qs][0], out[qs][1], out[qs][2], out[qs][3]};
            *(f32x4*)(r + 4)  = (f32x4){out[qs][4], out[qs][5], out[qs][6], out[qs][7]};
            *(f32x4*)(r + 8)  = (f32x4){out[qs][8], out[qs][9], out[qs][10], out[qs][11]};
            *(f32x4*)(r + 12) = (f32x4){out[qs][12], out[qs][13], out[qs][14], out[qs][15]};
            r[16] = myL;
        }
        __syncthreads();
        if (kh == 0) {
            f32x16 o = out[qs];
            float l = myL;
#pragma unroll
            for (int j = 0; j < 3; ++j) {
                const float* r = red + ((j * 2 + qg) * 64 + lane) * 20;
#pragma unroll
                for (int i = 0; i < 16; ++i) o[i] += r[i];
                l += r[16];
            }
            float inv = __builtin_amdgcn_rcpf(l);
            bf16* Ob = O + ((size_t)b * N + qbase + qs * 32 + l31) * CDIM + hh * DH;
#pragma unroll
            for (int rg = 0; rg < 4; ++rg) {
                const int d0 = rg * 8 + h * 4;  // C rows: (reg&3)+8*(reg>>2)+4*h
                bf16x4 v = {(bf16)(o[rg * 4 + 0] * inv), (bf16)(o[rg * 4 + 1] * inv),
                            (bf16)(o[rg * 4 + 2] * inv), (bf16)(o[rg * 4 + 3] * inv)};
                *(bf16x4*)(Ob + d0) = v;
            }
        }
    }
}

// ---------------- output projection ----------------
// A: [b][n][128] bf16 ; out: [b][128][4096] f32 with bias. grid.z splits ot.
__global__ __launch_bounds__(256) void proj_o(const bf16* __restrict__ A,
                                              const bf16* __restrict__ W,
                                              const float* __restrict__ bo,
                                              float* __restrict__ out) {
    const int b = blockIdx.y;
    const int n0 = blockIdx.x * 64;
    __shared__ __align__(16) bf16 aT[64][136];  // [n][c]
    const int tid = threadIdx.x;
    const bf16* Ab = A + (size_t)b * N * CDIM;
    for (int i = tid; i < 64 * 16; i += 256) {  // 4 b128 copies per thread
        int c8 = (i & 15) * 8, n = i >> 4;
        *(bf16x8*)&aT[n][c8] = *(const bf16x8*)&Ab[(size_t)(n0 + n) * CDIM + c8];
    }
    __syncthreads();

    const int lane = tid & 63, w = tid >> 6;
    const int cr = lane & 15, quad = lane >> 4;
    const bf16* Wm = W + 3 * 16384;  // wo
    const int ot = blockIdx.z * 4 + w;

    for (int nt = 0; nt < 4; ++nt) {
        bf16x8 bfr[4];
#pragma unroll
        for (int ks = 0; ks < 4; ++ks)
            bfr[ks] = *(const bf16x8*)&aT[nt * 16 + cr][ks * 32 + quad * 8];
        f32x4 acc = {0.f, 0.f, 0.f, 0.f};
#pragma unroll
        for (int ks = 0; ks < 4; ++ks) {
            bf16x8 afr = *(const bf16x8*)&Wm[(ot * 16 + cr) * 128 + ks * 32 + quad * 8];
            acc = MFMA16(afr, bfr[ks], acc);
        }
        int n = n0 + nt * 16 + cr;
        int o0 = ot * 16 + quad * 4;
#pragma unroll
        for (int r = 0; r < 4; ++r)
            out[((size_t)b * CDIM + o0 + r) * N + n] = acc[r] + bo[o0 + r];
    }
}

// ---------------- launch ----------------
extern "C" void kernel_launch(void* const* d_in, const int* in_sizes, int n_in,
                              void* d_out, int out_size, void* d_ws, size_t ws_size,
                              hipStream_t stream) {
    const float* x  = (const float*)d_in[0];
    const float* wq = (const float*)d_in[1];
    const float* wk = (const float*)d_in[2];
    const float* wv = (const float*)d_in[3];
    const float* wo = (const float*)d_in[4];
    const float* bo = (const float*)d_in[5];

    char* ws = (char*)d_ws;
    bf16* Q = (bf16*)(ws);                       // 4 MB  [bh][n][32]
    bf16* K = (bf16*)(ws + ((size_t)4 << 20));   // 4 MB  [bh][n][32]
    bf16* V = (bf16*)(ws + ((size_t)8 << 20));   // 4 MB  [bh][tile][d32][kperm64]
    bf16* A = (bf16*)(ws + ((size_t)12 << 20));  // 4 MB  [b][n][128]
    bf16* W = (bf16*)(ws + ((size_t)16 << 20));  // 128 KB

    cvt_w<<<64, 256, 0, stream>>>(wq, wk, wv, wo, W);
    proj_qkv<<<dim3(64, 4, 3), 256, 0, stream>>>(x, W, Q, K, V);
    flash<<<512, 512, 0, stream>>>(Q, K, V, A);
    proj_o<<<dim3(64, 4, 2), 256, 0, stream>>>(A, W, bo, (float*)d_out);
}